// Round 1
// baseline (231.506 us; speedup 1.0000x reference)
//
#include <hip/hip_runtime.h>

#define K_CB 243  // codebook size for (BIT_WIDTH=8, M=2)

// Elementwise APoT quantizer, eval-mode forward:
//   alpha_pos = |alpha| + 1e-5
//   xn = clip(x / alpha_pos, -1, 1)          (IEEE divide: bit-match numpy)
//   i  = clip(lower_bound(cb, xn), 1, K-1)   (searchsorted side='left')
//   q  = |xn-cb[i-1]| <= |xn-cb[i]| ? cb[i-1] : cb[i]   (tie -> left)
//   out = q * alpha_pos
__global__ __launch_bounds__(256) void apot_quant_kernel(
    const float* __restrict__ x,
    const float* __restrict__ alpha,
    const float* __restrict__ codebook,
    float* __restrict__ out,
    int n)
{
    __shared__ float cb[K_CB];
    if (threadIdx.x < K_CB) cb[threadIdx.x] = codebook[threadIdx.x];
    __syncthreads();

    const float alpha_pos = fabsf(alpha[0]) + 1e-5f;

    const int tid = blockIdx.x * blockDim.x + threadIdx.x;
    const int base = tid * 4;

    float r[4];
    float q[4];

    if (base + 3 < n) {
        const float4 v = *(const float4*)(x + base);
        r[0] = v.x; r[1] = v.y; r[2] = v.z; r[3] = v.w;

        #pragma unroll
        for (int e = 0; e < 4; ++e) {
            // IEEE divide (no fast-math) so xn bit-matches the np reference;
            // the midpoint tie-break below is 1-ulp sensitive.
            float xn = r[e] / alpha_pos;
            xn = fminf(1.0f, fmaxf(-1.0f, xn));

            // lower_bound over cb[0..K_CB): first index with cb[idx] >= xn.
            int lo = 0, hi = K_CB;
            #pragma unroll
            for (int it = 0; it < 8; ++it) {  // 2^8 = 256 >= 243+1
                int mid = (lo + hi) >> 1;
                bool lt = (cb[mid] < xn);
                lo = lt ? (mid + 1) : lo;
                hi = lt ? hi : mid;
            }
            int i = lo;
            i = (i < 1) ? 1 : i;
            i = (i > K_CB - 1) ? (K_CB - 1) : i;

            const float left  = cb[i - 1];
            const float right = cb[i];
            const float ql = (fabsf(xn - left) <= fabsf(xn - right)) ? left : right;
            q[e] = ql * alpha_pos;
        }

        *(float4*)(out + base) = make_float4(q[0], q[1], q[2], q[3]);
    } else if (base < n) {
        // scalar tail (not hit for 4096x8192, kept for generality)
        for (int e = 0; e < 4 && base + e < n; ++e) {
            float xn = x[base + e] / alpha_pos;
            xn = fminf(1.0f, fmaxf(-1.0f, xn));
            int lo = 0, hi = K_CB;
            for (int it = 0; it < 8; ++it) {
                int mid = (lo + hi) >> 1;
                bool lt = (cb[mid] < xn);
                lo = lt ? (mid + 1) : lo;
                hi = lt ? hi : mid;
            }
            int i = lo;
            i = (i < 1) ? 1 : i;
            i = (i > K_CB - 1) ? (K_CB - 1) : i;
            const float left  = cb[i - 1];
            const float right = cb[i];
            const float ql = (fabsf(xn - left) <= fabsf(xn - right)) ? left : right;
            out[base + e] = ql * alpha_pos;
        }
    }
}

extern "C" void kernel_launch(void* const* d_in, const int* in_sizes, int n_in,
                              void* d_out, int out_size, void* d_ws, size_t ws_size,
                              hipStream_t stream) {
    const float* x        = (const float*)d_in[0];
    const float* alpha    = (const float*)d_in[1];
    const float* codebook = (const float*)d_in[2];
    float* out            = (float*)d_out;

    const int n = in_sizes[0];            // 33,554,432
    const int n4 = (n + 3) / 4;           // elements per thread = 4
    const int block = 256;
    const int grid = (n4 + block - 1) / block;

    apot_quant_kernel<<<grid, block, 0, stream>>>(x, alpha, codebook, out, n);
}

// Round 2
// 225.398 us; speedup vs baseline: 1.0271x; 1.0271x over previous
//
#include <hip/hip_runtime.h>

// APoT (8-bit, m=2) quantizer, eval forward — LDS-free bit-logic version.
//
// Codebook = {0, ±2^-p (p=0..15), ±(2^-p + 2^-q) (1<=p<q<=15)}: every level is
// an fp32 with at most TWO mantissa bits set, second bit >= 2^-15 absolute.
// Nearest-level with searchsorted/argmin-first tie-break reduces to exact
// integer comparisons on the bit pattern of |xn| (all reference fp32
// subtractions are exact by Sterbenz / integer-scaling), so this matches the
// numpy reference bit-for-bit with ZERO table lookups.
//
// Tie semantics (|xn-left| <= |xn-right| picks left = smaller index):
//   xn > 0: tie -> smaller value (lo);  xn < 0: tie -> larger magnitude (hi).

__device__ __forceinline__ float apot_q(float xn) {
    const unsigned u = __float_as_uint(xn);
    const unsigned s = u & 0x80000000u;
    const unsigned a = u & 0x7FFFFFFFu;   // |xn| bits, <= 0x3F800000 (1.0f)
    unsigned q;
    if (a >= 0x38000000u) {               // |xn| >= 2^-15 : ~99.999% of data
        const unsigned e    = a >> 23;          // 112..127
        const unsigned m    = a & 0x7FFFFFu;
        const unsigned base = a - m;            // e<<23
        const unsigned g    = 1u << (135u - e); // finest grid bit (abs 2^-15)
        const unsigned L    = 31u - __clz(m | 1u);
        const unsigned bit  = 1u << L;
        const bool fine = (m < g);
        // adjacent levels bracketing |xn| (bit-pattern add carries into exp)
        const unsigned lo  = fine ? base      : (base | bit);
        const unsigned hi  = fine ? (base + g): (base + (bit << 1));
        // decision: 2m vs (lo+hi midpoint mantissa): g (fine) or 3*2^L
        const unsigned mid = fine ? g : (bit + (bit << 1));
        const unsigned m2  = m + m;
        const bool pickLo = (m2 < mid) | ((m2 == mid) & (s == 0u));
        q = pickLo ? lo : hi;
        // exact-level inputs (m==0 or m==bit): m2 < mid -> lo == a. correct.
    } else {
        // |xn| < 2^-15: neighbors are {0, 2^-15}; midpoint 2^-16 (exact cmp)
        const unsigned T0 = 0x37800000u;  // 2^-16
        const bool pickZero = (a < T0) | ((a == T0) & (s == 0u));
        q = pickZero ? 0u : 0x38000000u;
    }
    return __uint_as_float(q | s);
}

__global__ __launch_bounds__(256) void apot_quant_kernel(
    const float* __restrict__ x,
    const float* __restrict__ alpha,
    float* __restrict__ out,
    int n)
{
    const float alpha_pos = fabsf(alpha[0]) + 1e-5f;

    const int tid  = blockIdx.x * blockDim.x + threadIdx.x;
    const int base = tid * 4;

    if (base + 3 < n) {
        const float4 v = *(const float4*)(x + base);
        float4 o;
        // IEEE RN divide (no fast-math): xn must bit-match np for exactness.
        float xn0 = fminf(1.0f, fmaxf(-1.0f, v.x / alpha_pos));
        float xn1 = fminf(1.0f, fmaxf(-1.0f, v.y / alpha_pos));
        float xn2 = fminf(1.0f, fmaxf(-1.0f, v.z / alpha_pos));
        float xn3 = fminf(1.0f, fmaxf(-1.0f, v.w / alpha_pos));
        o.x = apot_q(xn0) * alpha_pos;
        o.y = apot_q(xn1) * alpha_pos;
        o.z = apot_q(xn2) * alpha_pos;
        o.w = apot_q(xn3) * alpha_pos;
        *(float4*)(out + base) = o;
    } else if (base < n) {
        for (int e = 0; e < 4 && base + e < n; ++e) {
            float xn = fminf(1.0f, fmaxf(-1.0f, x[base + e] / alpha_pos));
            out[base + e] = apot_q(xn) * alpha_pos;
        }
    }
}

extern "C" void kernel_launch(void* const* d_in, const int* in_sizes, int n_in,
                              void* d_out, int out_size, void* d_ws, size_t ws_size,
                              hipStream_t stream) {
    const float* x     = (const float*)d_in[0];
    const float* alpha = (const float*)d_in[1];
    // d_in[2] (codebook) is implied by the bit logic; not read.
    float* out         = (float*)d_out;

    const int n  = in_sizes[0];           // 33,554,432
    const int n4 = (n + 3) / 4;
    const int block = 256;
    const int grid  = (n4 + block - 1) / block;

    apot_quant_kernel<<<grid, block, 0, stream>>>(x, alpha, out, n);
}

// Round 3
// 222.589 us; speedup vs baseline: 1.0401x; 1.0126x over previous
//
#include <hip/hip_runtime.h>

// APoT (8-bit, m=2) quantizer, eval forward — LDS-free bit-logic version.
//
// Codebook = {0, ±2^-p (p=1..15), ±(2^-p + 2^-q) (1<=p<q<=15), ±1}: every
// level is an fp32 with at most TWO mantissa bits set, finest bit 2^-15
// absolute. Nearest-level with searchsorted/argmin-first tie-break reduces to
// exact integer comparisons on the bit pattern of |xn| (all reference fp32
// subtractions are exact: same-binade diffs are integer-scaled, cross-binade
// is Sterbenz), so this matches the numpy reference bit-for-bit with ZERO
// table lookups. Verified absmax == 0.0 in R1.
//
// Tie semantics (|xn-left| <= |xn-right| picks left = smaller index):
//   xn > 0: tie -> smaller value (lo);  xn < 0: tie -> larger magnitude (hi).

typedef float vfloat4 __attribute__((ext_vector_type(4)));

__device__ __forceinline__ float apot_q(float xn) {
    const unsigned u = __float_as_uint(xn);
    const unsigned s = u & 0x80000000u;
    const unsigned a = u & 0x7FFFFFFFu;   // |xn| bits, <= 0x3F800000 (1.0f)
    unsigned q;
    if (a >= 0x38000000u) {               // |xn| >= 2^-15 : ~99.999% of data
        const unsigned e    = a >> 23;          // 112..127
        const unsigned m    = a & 0x7FFFFFu;
        const unsigned base = a - m;            // e<<23
        const unsigned g    = 1u << (135u - e); // finest grid bit (abs 2^-15)
        const unsigned L    = 31u - __clz(m | 1u);
        const unsigned bit  = 1u << L;
        const bool fine = (m < g);
        // adjacent levels bracketing |xn| (bit-pattern add carries into exp)
        const unsigned lo  = fine ? base       : (base | bit);
        const unsigned hi  = fine ? (base + g) : (base + (bit << 1));
        // decision: 2m vs midpoint mantissa: g (fine) or 3*2^L (coarse)
        const unsigned mid = fine ? g : (bit + (bit << 1));
        const unsigned m2  = m + m;
        const bool pickLo = (m2 < mid) | ((m2 == mid) & (s == 0u));
        q = pickLo ? lo : hi;
    } else {
        // |xn| < 2^-15: neighbors {0, 2^-15}; midpoint 2^-16 (exact compare)
        const unsigned T0 = 0x37800000u;  // 2^-16
        const bool pickZero = (a < T0) | ((a == T0) & (s == 0u));
        q = pickZero ? 0u : 0x38000000u;
    }
    return __uint_as_float(q | s);
}

__device__ __forceinline__ vfloat4 quant4(vfloat4 v, float alpha_pos) {
    vfloat4 o;
    #pragma unroll
    for (int e = 0; e < 4; ++e) {
        // IEEE RN divide (no fast-math): xn must bit-match np for exactness.
        float xn = fminf(1.0f, fmaxf(-1.0f, v[e] / alpha_pos));
        o[e] = apot_q(xn) * alpha_pos;
    }
    return o;
}

// 8 elements/thread: two coalesced dwordx4 streams, both loads issued before
// any dependent ALU; non-temporal (touch-once data, skip L2 retention).
__global__ __launch_bounds__(256) void apot_quant_kernel(
    const float* __restrict__ x,
    const float* __restrict__ alpha,
    float* __restrict__ out,
    int n)
{
    const float alpha_pos = fabsf(alpha[0]) + 1e-5f;

    const int blockStart = blockIdx.x * (256 * 8);
    const int i0 = blockStart + (int)threadIdx.x * 4;       // stream 0
    const int i1 = i0 + 256 * 4;                            // stream 1

    if (i1 + 3 < n) {
        vfloat4 v0 = __builtin_nontemporal_load((const vfloat4*)(x + i0));
        vfloat4 v1 = __builtin_nontemporal_load((const vfloat4*)(x + i1));
        vfloat4 o0 = quant4(v0, alpha_pos);
        vfloat4 o1 = quant4(v1, alpha_pos);
        __builtin_nontemporal_store(o0, (vfloat4*)(out + i0));
        __builtin_nontemporal_store(o1, (vfloat4*)(out + i1));
    } else {
        // generic tail (not hit for 4096x8192: n % 2048 == 0)
        for (int k = 0; k < 8; ++k) {
            int idx = blockStart + (int)threadIdx.x * 4;
            idx = (k < 4) ? (idx + k) : (idx + 1024 + (k - 4));
            if (idx < n) {
                float xn = fminf(1.0f, fmaxf(-1.0f, x[idx] / alpha_pos));
                out[idx] = apot_q(xn) * alpha_pos;
            }
        }
    }
}

extern "C" void kernel_launch(void* const* d_in, const int* in_sizes, int n_in,
                              void* d_out, int out_size, void* d_ws, size_t ws_size,
                              hipStream_t stream) {
    const float* x     = (const float*)d_in[0];
    const float* alpha = (const float*)d_in[1];
    // d_in[2] (codebook) is implied by the bit logic; not read.
    float* out         = (float*)d_out;

    const int n = in_sizes[0];            // 33,554,432
    const int elemsPerBlock = 256 * 8;
    const int grid = (n + elemsPerBlock - 1) / elemsPerBlock;  // 16384

    apot_quant_kernel<<<grid, 256, 0, stream>>>(x, alpha, out, n);
}